// Round 1
// baseline (2611.996 us; speedup 1.0000x reference)
//
#include <hip/hip_runtime.h>
#include <hip/hip_bf16.h>

typedef __bf16 bf16x8 __attribute__((ext_vector_type(8)));
typedef float  f32x4  __attribute__((ext_vector_type(4)));
typedef unsigned short u16;
typedef unsigned int   u32;

#define DEV __device__ __forceinline__

DEV float bu2f(u16 u){ union{u32 i; float f;} x; x.i=((u32)u)<<16; return x.f; }
DEV u16 f2bu(float f){ union{float f; u32 i;} x; x.f=f; u32 r=x.i+0x7FFFu+((x.i>>16)&1u); return (u16)(r>>16); }
DEV u32 pack2(float a, float b){ return (u32)f2bu(a) | ((u32)f2bu(b)<<16); }

DEV void gload16(const void* g, void* l){
  __builtin_amdgcn_global_load_lds((const __attribute__((address_space(1))) void*)g,
                                   (__attribute__((address_space(3))) void*)l, 16, 0, 0);
}

// ------------------------------------------------------------------
// GEMM: C[M,N] = A[M,K](bf16,row-major) x Bt[N,K](bf16,row-major)^T
// 128x128 tile, BK=64, 4 waves (2x2 of 64x64), mfma_f32_16x16x32_bf16.
// LDS XOR-swizzle (granule ^= row&7) applied on BOTH global source and
// ds_read address (rule #21) -> conflict-free ds_read_b128.
// ------------------------------------------------------------------
template<int BIAS, int GELU, int RESF32, int OUTF32>
__global__ __launch_bounds__(256) void gemm_bt(
    const u16* __restrict__ A, const u16* __restrict__ Bt,
    const float* __restrict__ bias, const float* __restrict__ resid,
    float* __restrict__ outF, u16* __restrict__ outB,
    int M, int N, int K,
    long long sA, long long sB, long long sC)
{
  __shared__ __align__(16) u16 As[128*64];
  __shared__ __align__(16) u16 Bs[128*64];
  const int tid  = threadIdx.x;
  const int lane = tid & 63;
  const int wave = tid >> 6;
  const int wm = wave >> 1, wn = wave & 1;
  const int rowBase = blockIdx.y * 128;
  const int colBase = blockIdx.x * 128;
  const long long z = blockIdx.z;

  const u16* Ag = A + z*sA + (size_t)rowBase * K;
  const u16* Bg = Bt + z*sB + (size_t)colBase * K;

  const int srow = lane >> 3;                 // row within 8-row staging chunk
  const int scol = ((lane & 7) ^ srow) * 8;   // pre-swizzled source k-offset
  const int q   = lane >> 4;
  const int s7  = lane & 7;
  const int r15 = lane & 15;

  f32x4 acc[4][4];
  const f32x4 fzero = {0.f,0.f,0.f,0.f};
#pragma unroll
  for (int m=0;m<4;++m)
#pragma unroll
    for (int n=0;n<4;++n) acc[m][n]=fzero;

  for (int kt=0; kt<K; kt+=64){
#pragma unroll
    for (int i=0;i<4;++i){
      const int c = wave*4 + i;
      gload16(Ag + (size_t)(c*8+srow)*K + kt + scol, (void*)(As + c*512 + lane*8));
      gload16(Bg + (size_t)(c*8+srow)*K + kt + scol, (void*)(Bs + c*512 + lane*8));
    }
    __syncthreads();   // compiler drains vmcnt(0) here
#pragma unroll
    for (int h=0; h<2; ++h){
      bf16x8 av[4], bv4[4];
#pragma unroll
      for (int m=0;m<4;++m)
        av[m]  = *reinterpret_cast<const bf16x8*>(&As[(wm*64+m*16+r15)*64 + (((h*4+q)^s7)*8)]);
#pragma unroll
      for (int n=0;n<4;++n)
        bv4[n] = *reinterpret_cast<const bf16x8*>(&Bs[(wn*64+n*16+r15)*64 + (((h*4+q)^s7)*8)]);
#pragma unroll
      for (int m=0;m<4;++m)
#pragma unroll
        for (int n=0;n<4;++n)
          acc[m][n] = __builtin_amdgcn_mfma_f32_16x16x32_bf16(av[m], bv4[n], acc[m][n], 0,0,0);
    }
    __syncthreads();
  }

  const long long cb = z*sC;
#pragma unroll
  for (int m=0;m<4;++m){
    const int row0 = rowBase + wm*64 + m*16 + q*4;
#pragma unroll
    for (int n=0;n<4;++n){
      const int col = colBase + wn*64 + n*16 + r15;
      float bb = 0.f;
      if (BIAS) bb = bias[col];
#pragma unroll
      for (int r=0;r<4;++r){
        float v = acc[m][n][r] + bb;
        if (GELU) v = 0.5f*v*(1.f+erff(v*0.70710678118654752f));
        const size_t oi = (size_t)cb + (size_t)(row0+r)*N + col;
        if (RESF32) v += resid[oi];
        if (OUTF32) outF[oi] = v;
        else        outB[oi] = f2bu(v);
      }
    }
  }
}

// ----------------- f32 [R][C] -> bf16 [C][R] (LDS-tiled) -----------------
__global__ __launch_bounds__(256) void tr_f32_bf16(
    const float* __restrict__ in, u16* __restrict__ out, int R, int C)
{
  __shared__ float tile[64][65];
  const int t = threadIdx.x;
  const int tr = blockIdx.y*64, tc = blockIdx.x*64;
  const int c4 = (t&15)*4;
#pragma unroll
  for (int i=0;i<4;++i){
    const int r = i*16 + (t>>4);
    const float4 v = *reinterpret_cast<const float4*>(&in[(size_t)(tr+r)*C + tc + c4]);
    tile[r][c4+0]=v.x; tile[r][c4+1]=v.y; tile[r][c4+2]=v.z; tile[r][c4+3]=v.w;
  }
  __syncthreads();
#pragma unroll
  for (int i=0;i<4;++i){
    const int c = i*16 + (t>>4);
    uint2 o;
    o.x = pack2(tile[c4+0][c], tile[c4+1][c]);
    o.y = pack2(tile[c4+2][c], tile[c4+3][c]);
    *reinterpret_cast<uint2*>(&out[(size_t)(tc+c)*R + tr + c4]) = o;
  }
}

// ----------------- bf16 [R][C] -> bf16 [C][R], batched -----------------
__global__ __launch_bounds__(256) void tr_bf16(
    const u16* __restrict__ in, u16* __restrict__ out, int R, int C,
    long long sIn, long long sOut)
{
  __shared__ u16 tile[64][72];
  const long long z = blockIdx.z;
  in  += z*sIn; out += z*sOut;
  const int t = threadIdx.x;
  const int tr = blockIdx.y*64, tc = blockIdx.x*64;
  const int c4 = (t&15)*4;
#pragma unroll
  for (int i=0;i<4;++i){
    const int r = i*16 + (t>>4);
    const uint2 v = *reinterpret_cast<const uint2*>(&in[(size_t)(tr+r)*C + tc + c4]);
    tile[r][c4+0]=(u16)(v.x&0xffffu); tile[r][c4+1]=(u16)(v.x>>16);
    tile[r][c4+2]=(u16)(v.y&0xffffu); tile[r][c4+3]=(u16)(v.y>>16);
  }
  __syncthreads();
#pragma unroll
  for (int i=0;i<4;++i){
    const int c = i*16 + (t>>4);
    uint2 o;
    o.x = (u32)tile[c4+0][c] | ((u32)tile[c4+1][c]<<16);
    o.y = (u32)tile[c4+2][c] | ((u32)tile[c4+3][c]<<16);
    *reinterpret_cast<uint2*>(&out[(size_t)(tc+c)*R + tr + c4]) = o;
  }
}

// ----------------- flat f32 -> bf16 -----------------
__global__ __launch_bounds__(256) void cvt_f32_bf16(
    const float* __restrict__ in, u16* __restrict__ out, int n4)
{
  const int i = blockIdx.x*256 + threadIdx.x;
  if (i >= n4) return;
  const float4 v = reinterpret_cast<const float4*>(in)[i];
  uint2 o; o.x = pack2(v.x,v.y); o.y = pack2(v.z,v.w);
  reinterpret_cast<uint2*>(out)[i] = o;
}

// ----------------- row softmax, row length 2048, scale folded -----------------
__global__ __launch_bounds__(256) void softmax2048(
    const float* __restrict__ S, u16* __restrict__ P, float scale)
{
  const size_t row = blockIdx.x;
  const float4* src = reinterpret_cast<const float4*>(S + row*2048);
  const int t = threadIdx.x, lane = t&63, wave = t>>6;
  const float4 a = src[t], b = src[t+256];
  float v[8] = {a.x,a.y,a.z,a.w,b.x,b.y,b.z,b.w};
  float m = -3.4e38f;
#pragma unroll
  for (int i=0;i<8;++i){ v[i]*=scale; m = fmaxf(m, v[i]); }
#pragma unroll
  for (int o=32;o>0;o>>=1) m = fmaxf(m, __shfl_xor(m, o));
  __shared__ float red[8];
  if (lane==0) red[wave]=m;
  __syncthreads();
  m = fmaxf(fmaxf(red[0],red[1]), fmaxf(red[2],red[3]));
  float s = 0.f;
#pragma unroll
  for (int i=0;i<8;++i){ v[i] = __expf(v[i]-m); s += v[i]; }
#pragma unroll
  for (int o=32;o>0;o>>=1) s += __shfl_xor(s, o);
  if (lane==0) red[4+wave]=s;
  __syncthreads();
  s = red[4]+red[5]+red[6]+red[7];
  const float r = 1.f/s;
  uint2 o1, o2;
  o1.x = pack2(v[0]*r, v[1]*r); o1.y = pack2(v[2]*r, v[3]*r);
  o2.x = pack2(v[4]*r, v[5]*r); o2.y = pack2(v[6]*r, v[7]*r);
  uint2* dst = reinterpret_cast<uint2*>(P + row*2048);
  dst[t] = o1; dst[t+256] = o2;
}

// ----------------- row LayerNorm, row length 4096 -----------------
template<int WB>
__global__ __launch_bounds__(256) void layernorm4096(
    const float* __restrict__ X, const float* __restrict__ g,
    const float* __restrict__ b, float* __restrict__ Yf, u16* __restrict__ Yb)
{
  const size_t row = blockIdx.x;
  const float4* src = reinterpret_cast<const float4*>(X + row*4096);
  const int t = threadIdx.x, lane = t&63, wave = t>>6;
  float4 xv[4];
  float sum=0.f, ss=0.f;
#pragma unroll
  for (int i=0;i<4;++i){
    xv[i] = src[t + 256*i];
    sum += xv[i].x+xv[i].y+xv[i].z+xv[i].w;
    ss  += xv[i].x*xv[i].x + xv[i].y*xv[i].y + xv[i].z*xv[i].z + xv[i].w*xv[i].w;
  }
#pragma unroll
  for (int o=32;o>0;o>>=1){ sum += __shfl_xor(sum,o); ss += __shfl_xor(ss,o); }
  __shared__ float rs[4], rq[4];
  if (lane==0){ rs[wave]=sum; rq[wave]=ss; }
  __syncthreads();
  sum = rs[0]+rs[1]+rs[2]+rs[3];
  ss  = rq[0]+rq[1]+rq[2]+rq[3];
  const float mean = sum * (1.f/4096.f);
  const float var  = ss * (1.f/4096.f) - mean*mean;
  const float rstd = rsqrtf(var + 1e-5f);
#pragma unroll
  for (int i=0;i<4;++i){
    const int i4 = t + 256*i;
    const float4 gv = reinterpret_cast<const float4*>(g)[i4];
    const float4 bvv = reinterpret_cast<const float4*>(b)[i4];
    float4 y;
    y.x = (xv[i].x-mean)*rstd*gv.x + bvv.x;
    y.y = (xv[i].y-mean)*rstd*gv.y + bvv.y;
    y.z = (xv[i].z-mean)*rstd*gv.z + bvv.z;
    y.w = (xv[i].w-mean)*rstd*gv.w + bvv.w;
    reinterpret_cast<float4*>(Yf + row*4096)[i4] = y;
    if (WB){
      uint2 o; o.x = pack2(y.x,y.y); o.y = pack2(y.z,y.w);
      reinterpret_cast<uint2*>(Yb + row*4096)[i4] = o;
    }
  }
}

extern "C" void kernel_launch(void* const* d_in, const int* in_sizes, int n_in,
                              void* d_out, int out_size, void* d_ws, size_t ws_size,
                              hipStream_t stream)
{
  constexpr int D = 4096, HD = 16384, S = 2048, B = 2;
  constexpr int NT = B*S;           // 4096 rows total
  const float* x   = (const float*)d_in[0];
  const float* Wq  = (const float*)d_in[1];
  const float* bq  = (const float*)d_in[2];
  const float* Wk  = (const float*)d_in[3];
  const float* bk  = (const float*)d_in[4];
  const float* Wv  = (const float*)d_in[5];
  const float* bvp = (const float*)d_in[6];
  const float* Wo  = (const float*)d_in[7];
  const float* bo  = (const float*)d_in[8];
  const float* g1  = (const float*)d_in[9];
  const float* b1  = (const float*)d_in[10];
  const float* g2  = (const float*)d_in[11];
  const float* b2  = (const float*)d_in[12];
  const float* W1  = (const float*)d_in[13];
  const float* bi1 = (const float*)d_in[14];
  const float* W2  = (const float*)d_in[15];
  const float* bi2 = (const float*)d_in[16];

  // ---- workspace layout (phase-aliased; total 17*32MB = 544 MB) ----
  char* ws = (char*)d_ws;
  const size_t MB32 = 33554432;     // 32 MiB
  u16* WqT = (u16*)(ws + 0*MB32);
  u16* WkT = (u16*)(ws + 1*MB32);
  u16* WvT = (u16*)(ws + 2*MB32);
  u16* WoT = (u16*)(ws + 3*MB32);
  u16* W1T = (u16*)(ws + 0*MB32);   // phase B: aliases WqT..WoT (dead)
  u16* xb  = (u16*)(ws + 4*MB32);
  u16* Qb  = (u16*)(ws + 5*MB32);
  u16* Kb  = (u16*)(ws + 6*MB32);
  u16* Vb  = (u16*)(ws + 7*MB32);
  u16* W2T = (u16*)(ws + 4*MB32);   // phase B: aliases xb..Vb (dead)
  u16* Vt  = (u16*)(ws + 8*MB32);
  float* scoresF = (float*)(ws + 9*MB32);
  u16* Pb  = (u16*)(ws + 10*MB32);
  u16* Ab  = (u16*)(ws + 10*MB32 + 16777216);
  u16* hB  = (u16*)(ws + 8*MB32);   // phase B: [8..12)*32MB region
  float* x1raw = (float*)(ws + 12*MB32);
  float* x2raw = (float*)(ws + 12*MB32); // aliases x1raw (dead after LN1)
  float* x1f   = (float*)(ws + 14*MB32);
  u16*   x1b   = (u16*)(ws + 16*MB32);

  const dim3 blk(256);
  const long long SD = (long long)S*D, SS = (long long)S*S, DS = (long long)D*S;

  // weights -> bf16 transposed [N][K]
  tr_f32_bf16<<<dim3(D/64, D/64), blk, 0, stream>>>(Wq, WqT, D, D);
  tr_f32_bf16<<<dim3(D/64, D/64), blk, 0, stream>>>(Wk, WkT, D, D);
  tr_f32_bf16<<<dim3(D/64, D/64), blk, 0, stream>>>(Wv, WvT, D, D);
  tr_f32_bf16<<<dim3(D/64, D/64), blk, 0, stream>>>(Wo, WoT, D, D);
  cvt_f32_bf16<<<dim3((NT*D/4)/256), blk, 0, stream>>>(x, xb, NT*D/4);

  // Q,K,V projections
  gemm_bt<1,0,0,0><<<dim3(D/128, NT/128, 1), blk, 0, stream>>>(xb, WqT, bq,  nullptr, nullptr, Qb, NT, D, D, 0,0,0);
  gemm_bt<1,0,0,0><<<dim3(D/128, NT/128, 1), blk, 0, stream>>>(xb, WkT, bk,  nullptr, nullptr, Kb, NT, D, D, 0,0,0);
  gemm_bt<1,0,0,0><<<dim3(D/128, NT/128, 1), blk, 0, stream>>>(xb, WvT, bvp, nullptr, nullptr, Vb, NT, D, D, 0,0,0);
  tr_bf16<<<dim3(D/64, S/64, B), blk, 0, stream>>>(Vb, Vt, S, D, SD, SD);

  // attention: scores = Q K^T (f32), softmax(1/64), P V
  gemm_bt<0,0,0,1><<<dim3(S/128, S/128, B), blk, 0, stream>>>(Qb, Kb, nullptr, nullptr, scoresF, nullptr, S, S, D, SD, SD, SS);
  softmax2048<<<dim3(B*S), blk, 0, stream>>>(scoresF, Pb, 0.015625f);
  gemm_bt<0,0,0,0><<<dim3(D/128, S/128, B), blk, 0, stream>>>(Pb, Vt, nullptr, nullptr, nullptr, Ab, S, D, S, SS, DS, SD);

  // O projection + residual, LN1
  gemm_bt<1,0,1,1><<<dim3(D/128, NT/128, 1), blk, 0, stream>>>(Ab, WoT, bo, x, x1raw, nullptr, NT, D, D, 0,0,0);
  layernorm4096<1><<<dim3(NT), blk, 0, stream>>>(x1raw, g1, b1, x1f, x1b);

  // FFN
  tr_f32_bf16<<<dim3(HD/64, D/64), blk, 0, stream>>>(W1, W1T, D, HD);
  gemm_bt<1,1,0,0><<<dim3(HD/128, NT/128, 1), blk, 0, stream>>>(x1b, W1T, bi1, nullptr, nullptr, hB, NT, HD, D, 0,0,0);
  tr_f32_bf16<<<dim3(D/64, HD/64), blk, 0, stream>>>(W2, W2T, HD, D);
  gemm_bt<1,0,1,1><<<dim3(D/128, NT/128, 1), blk, 0, stream>>>(hB, W2T, bi2, x1f, x2raw, nullptr, NT, D, HD, 0,0,0);
  layernorm4096<0><<<dim3(NT), blk, 0, stream>>>(x2raw, g2, b2, (float*)d_out, nullptr);
}

// Round 2
// 2164.812 us; speedup vs baseline: 1.2066x; 1.2066x over previous
//
#include <hip/hip_runtime.h>
#include <hip/hip_bf16.h>

typedef __bf16 bf16x8 __attribute__((ext_vector_type(8)));
typedef float  f32x4  __attribute__((ext_vector_type(4)));
typedef unsigned short u16;
typedef unsigned int   u32;

#define DEV __device__ __forceinline__

DEV u16 f2bu(float f){ union{float f; u32 i;} x; x.f=f; u32 r=x.i+0x7FFFu+((x.i>>16)&1u); return (u16)(r>>16); }
DEV u32 pack2(float a, float b){ return (u32)f2bu(a) | ((u32)f2bu(b)<<16); }

DEV void gload16(const u16* g, u16* l){
  __builtin_amdgcn_global_load_lds((const __attribute__((address_space(1))) void*)g,
                                   (__attribute__((address_space(3))) void*)l, 16, 0, 0);
}

// ------------------------------------------------------------------
// GEMM: C[M,N] = A[M,K](bf16 rm) x Bt[N,K](bf16 rm)^T
// 256x256 tile, BK=32, 8 waves (2Mx4N), 4-buffer LDS rotation,
// counted vmcnt(8) (loads stay in flight across barriers), one
// s_barrier per K-tile, setprio around the 32-MFMA cluster.
// LDS XOR swizzle g' = q ^ ((row>>1)&3) applied on BOTH the
// pre-swizzled global_load_lds source and the ds_read address.
// ------------------------------------------------------------------
template<int BIAS, int GELU, int RESF32, int OUTF32>
__global__ __launch_bounds__(512, 2) void gemm256(
    const u16* __restrict__ A, const u16* __restrict__ Bt,
    const float* __restrict__ bias, const float* __restrict__ resid,
    float* __restrict__ outF, u16* __restrict__ outB,
    int M, int N, int K, int SWZ,
    long long sA, long long sB, long long sC)
{
  __shared__ __align__(16) u16 As[4][8192];   // [buf][256 rows][32 k]
  __shared__ __align__(16) u16 Bs[4][8192];

  const int tid  = threadIdx.x;
  const int lane = tid & 63;
  const int wave = tid >> 6;
  const int wm = wave >> 2;      // 0..1  -> 128 rows each
  const int wn = wave & 3;       // 0..3  -> 64 cols each

  int bx = blockIdx.x, by = blockIdx.y;
  if (SWZ) {
    const int gx = gridDim.x;
    const int nwg = gx * gridDim.y;          // caller guarantees nwg % 8 == 0
    const int flat = by * gx + bx;
    const int cpx = nwg >> 3;
    const int s = (flat & 7) * cpx + (flat >> 3);
    bx = s % gx; by = s / gx;
  }
  const int rowBase = by * 256;
  const int colBase = bx * 256;

  const u16* Ag = A + (size_t)blockIdx.z * sA + (size_t)rowBase * K;
  const u16* Bg = Bt + (size_t)blockIdx.z * sB + (size_t)colBase * K;

  // ---- staging addressing (write side of the swizzle) ----
  // wave w stages A rows [32w,32w+32) and B rows [32w,32w+32) per K-tile,
  // as 2 chunks of 16 rows each; lane l covers row chunk*16+(l>>2),
  // LDS granule (l&3), global k-quarter q = (l&3) ^ ((l>>3)&3).
  const int qsw = (lane & 3) ^ ((lane >> 3) & 3);
  const u16* apA0 = Ag + (size_t)(wave*32 + (lane>>2)) * K + qsw*8;
  const u16* apA1 = apA0 + (size_t)16 * K;
  const u16* apB0 = Bg + (size_t)(wave*32 + (lane>>2)) * K + qsw*8;
  const u16* apB1 = apB0 + (size_t)16 * K;
  u16* dA0 = &As[0][wave*1024 + lane*8];
  u16* dA1 = dA0 + 512;
  u16* dB0 = &Bs[0][wave*1024 + lane*8];
  u16* dB1 = dB0 + 512;

#define STAGE(t) { const int _b = (t) & 3; const size_t _k = (size_t)(t) * 32;          \
    gload16(apA0 + _k, dA0 + _b*8192); gload16(apA1 + _k, dA1 + _b*8192);               \
    gload16(apB0 + _k, dB0 + _b*8192); gload16(apB1 + _k, dB1 + _b*8192); }

  // ---- read addressing (read side of the swizzle) ----
  const int r15 = lane & 15;
  const int gp  = (lane >> 4) ^ ((lane >> 1) & 3);
  const u16* rdA = &As[0][(wm*128 + r15)*32 + gp*8];
  const u16* rdB = &Bs[0][(wn*64  + r15)*32 + gp*8];

  f32x4 acc[8][4];
  const f32x4 fz = {0.f,0.f,0.f,0.f};
#pragma unroll
  for (int m=0;m<8;++m)
#pragma unroll
    for (int n=0;n<4;++n) acc[m][n] = fz;

  const int KT = K >> 5;
  STAGE(0);
  if (KT > 1) STAGE(1);
  if (KT > 2) STAGE(2);

  for (int t = 0; t < KT; ++t) {
    const int rem = KT - t;
    if (rem > 2)      asm volatile("s_waitcnt vmcnt(8)" ::: "memory");
    else if (rem > 1) asm volatile("s_waitcnt vmcnt(4)" ::: "memory");
    else              asm volatile("s_waitcnt vmcnt(0)" ::: "memory");
    __builtin_amdgcn_s_barrier();
    asm volatile("" ::: "memory");   // compiler fence: no LDS reads above barrier

    const u16* pa = rdA + (t & 3) * 8192;
    const u16* pb = rdB + (t & 3) * 8192;
    bf16x8 a[8], b[4];
#pragma unroll
    for (int m=0;m<8;++m) a[m] = *(const bf16x8*)(pa + m*512);
#pragma unroll
    for (int n=0;n<4;++n) b[n] = *(const bf16x8*)(pb + n*512);

    if (t + 3 < KT) STAGE(t + 3);

    __builtin_amdgcn_s_setprio(1);
#pragma unroll
    for (int m=0;m<8;++m)
#pragma unroll
      for (int n=0;n<4;++n)
        acc[m][n] = __builtin_amdgcn_mfma_f32_16x16x32_bf16(a[m], b[n], acc[m][n], 0,0,0);
    __builtin_amdgcn_s_setprio(0);
  }
#undef STAGE

  const long long cb = (long long)blockIdx.z * sC;
  const int q4 = (lane >> 4) * 4;
#pragma unroll
  for (int m=0;m<8;++m){
    const int row0 = rowBase + wm*128 + m*16 + q4;
#pragma unroll
    for (int n=0;n<4;++n){
      const int col = colBase + wn*64 + n*16 + r15;
      float bb = 0.f;
      if (BIAS) bb = bias[col];
#pragma unroll
      for (int r=0;r<4;++r){
        float v = acc[m][n][r] + bb;
        if (GELU) v = 0.5f*v*(1.f+erff(v*0.70710678118654752f));
        const size_t oi = (size_t)cb + (size_t)(row0+r)*N + col;
        if (RESF32) v += resid[oi];
        if (OUTF32) outF[oi] = v;
        else        outB[oi] = f2bu(v);
      }
    }
  }
}

// ----------------- f32 [R][C] -> bf16 [C][R] (LDS-tiled) -----------------
__global__ __launch_bounds__(256) void tr_f32_bf16(
    const float* __restrict__ in, u16* __restrict__ out, int R, int C)
{
  __shared__ float tile[64][65];
  const int t = threadIdx.x;
  const int tr = blockIdx.y*64, tc = blockIdx.x*64;
  const int c4 = (t&15)*4;
#pragma unroll
  for (int i=0;i<4;++i){
    const int r = i*16 + (t>>4);
    const float4 v = *reinterpret_cast<const float4*>(&in[(size_t)(tr+r)*C + tc + c4]);
    tile[r][c4+0]=v.x; tile[r][c4+1]=v.y; tile[r][c4+2]=v.z; tile[r][c4+3]=v.w;
  }
  __syncthreads();
#pragma unroll
  for (int i=0;i<4;++i){
    const int c = i*16 + (t>>4);
    uint2 o;
    o.x = pack2(tile[c4+0][c], tile[c4+1][c]);
    o.y = pack2(tile[c4+2][c], tile[c4+3][c]);
    *reinterpret_cast<uint2*>(&out[(size_t)(tc+c)*R + tr + c4]) = o;
  }
}

// ----------------- bf16 [R][C] -> bf16 [C][R], batched -----------------
__global__ __launch_bounds__(256) void tr_bf16(
    const u16* __restrict__ in, u16* __restrict__ out, int R, int C,
    long long sIn, long long sOut)
{
  __shared__ u16 tile[64][72];
  const long long z = blockIdx.z;
  in  += z*sIn; out += z*sOut;
  const int t = threadIdx.x;
  const int tr = blockIdx.y*64, tc = blockIdx.x*64;
  const int c4 = (t&15)*4;
#pragma unroll
  for (int i=0;i<4;++i){
    const int r = i*16 + (t>>4);
    const uint2 v = *reinterpret_cast<const uint2*>(&in[(size_t)(tr+r)*C + tc + c4]);
    tile[r][c4+0]=(u16)(v.x&0xffffu); tile[r][c4+1]=(u16)(v.x>>16);
    tile[r][c4+2]=(u16)(v.y&0xffffu); tile[r][c4+3]=(u16)(v.y>>16);
  }
  __syncthreads();
#pragma unroll
  for (int i=0;i<4;++i){
    const int c = i*16 + (t>>4);
    uint2 o;
    o.x = (u32)tile[c4+0][c] | ((u32)tile[c4+1][c]<<16);
    o.y = (u32)tile[c4+2][c] | ((u32)tile[c4+3][c]<<16);
    *reinterpret_cast<uint2*>(&out[(size_t)(tc+c)*R + tr + c4]) = o;
  }
}

// ----------------- flat f32 -> bf16 -----------------
__global__ __launch_bounds__(256) void cvt_f32_bf16(
    const float* __restrict__ in, u16* __restrict__ out, int n4)
{
  const int i = blockIdx.x*256 + threadIdx.x;
  if (i >= n4) return;
  const float4 v = reinterpret_cast<const float4*>(in)[i];
  uint2 o; o.x = pack2(v.x,v.y); o.y = pack2(v.z,v.w);
  reinterpret_cast<uint2*>(out)[i] = o;
}

// ----------------- row softmax, row length 2048, scale folded -----------------
__global__ __launch_bounds__(256) void softmax2048(
    const float* __restrict__ S, u16* __restrict__ P, float scale)
{
  const size_t row = blockIdx.x;
  const float4* src = reinterpret_cast<const float4*>(S + row*2048);
  const int t = threadIdx.x, lane = t&63, wave = t>>6;
  const float4 a = src[t], b = src[t+256];
  float v[8] = {a.x,a.y,a.z,a.w,b.x,b.y,b.z,b.w};
  float m = -3.4e38f;
#pragma unroll
  for (int i=0;i<8;++i){ v[i]*=scale; m = fmaxf(m, v[i]); }
#pragma unroll
  for (int o=32;o>0;o>>=1) m = fmaxf(m, __shfl_xor(m, o));
  __shared__ float red[8];
  if (lane==0) red[wave]=m;
  __syncthreads();
  m = fmaxf(fmaxf(red[0],red[1]), fmaxf(red[2],red[3]));
  float s = 0.f;
#pragma unroll
  for (int i=0;i<8;++i){ v[i] = __expf(v[i]-m); s += v[i]; }
#pragma unroll
  for (int o=32;o>0;o>>=1) s += __shfl_xor(s, o);
  if (lane==0) red[4+wave]=s;
  __syncthreads();
  s = red[4]+red[5]+red[6]+red[7];
  const float r = 1.f/s;
  uint2 o1, o2;
  o1.x = pack2(v[0]*r, v[1]*r); o1.y = pack2(v[2]*r, v[3]*r);
  o2.x = pack2(v[4]*r, v[5]*r); o2.y = pack2(v[6]*r, v[7]*r);
  uint2* dst = reinterpret_cast<uint2*>(P + row*2048);
  dst[t] = o1; dst[t+256] = o2;
}

// ----------------- row LayerNorm, row length 4096 -----------------
template<int WB>
__global__ __launch_bounds__(256) void layernorm4096(
    const float* __restrict__ X, const float* __restrict__ g,
    const float* __restrict__ b, float* __restrict__ Yf, u16* __restrict__ Yb)
{
  const size_t row = blockIdx.x;
  const float4* src = reinterpret_cast<const float4*>(X + row*4096);
  const int t = threadIdx.x, lane = t&63, wave = t>>6;
  float4 xv[4];
  float sum=0.f, ss=0.f;
#pragma unroll
  for (int i=0;i<4;++i){
    xv[i] = src[t + 256*i];
    sum += xv[i].x+xv[i].y+xv[i].z+xv[i].w;
    ss  += xv[i].x*xv[i].x + xv[i].y*xv[i].y + xv[i].z*xv[i].z + xv[i].w*xv[i].w;
  }
#pragma unroll
  for (int o=32;o>0;o>>=1){ sum += __shfl_xor(sum,o); ss += __shfl_xor(ss,o); }
  __shared__ float rs[4], rq[4];
  if (lane==0){ rs[wave]=sum; rq[wave]=ss; }
  __syncthreads();
  sum = rs[0]+rs[1]+rs[2]+rs[3];
  ss  = rq[0]+rq[1]+rq[2]+rq[3];
  const float mean = sum * (1.f/4096.f);
  const float var  = ss * (1.f/4096.f) - mean*mean;
  const float rstd = rsqrtf(var + 1e-5f);
#pragma unroll
  for (int i=0;i<4;++i){
    const int i4 = t + 256*i;
    const float4 gv = reinterpret_cast<const float4*>(g)[i4];
    const float4 bvv = reinterpret_cast<const float4*>(b)[i4];
    float4 y;
    y.x = (xv[i].x-mean)*rstd*gv.x + bvv.x;
    y.y = (xv[i].y-mean)*rstd*gv.y + bvv.y;
    y.z = (xv[i].z-mean)*rstd*gv.z + bvv.z;
    y.w = (xv[i].w-mean)*rstd*gv.w + bvv.w;
    reinterpret_cast<float4*>(Yf + row*4096)[i4] = y;
    if (WB){
      uint2 o; o.x = pack2(y.x,y.y); o.y = pack2(y.z,y.w);
      reinterpret_cast<uint2*>(Yb + row*4096)[i4] = o;
    }
  }
}

extern "C" void kernel_launch(void* const* d_in, const int* in_sizes, int n_in,
                              void* d_out, int out_size, void* d_ws, size_t ws_size,
                              hipStream_t stream)
{
  constexpr int D = 4096, HD = 16384, S = 2048, B = 2;
  constexpr int NT = B*S;           // 4096 rows total
  const float* x   = (const float*)d_in[0];
  const float* Wq  = (const float*)d_in[1];
  const float* bq  = (const float*)d_in[2];
  const float* Wk  = (const float*)d_in[3];
  const float* bk  = (const float*)d_in[4];
  const float* Wv  = (const float*)d_in[5];
  const float* bvp = (const float*)d_in[6];
  const float* Wo  = (const float*)d_in[7];
  const float* bo  = (const float*)d_in[8];
  const float* g1  = (const float*)d_in[9];
  const float* b1  = (const float*)d_in[10];
  const float* g2  = (const float*)d_in[11];
  const float* b2  = (const float*)d_in[12];
  const float* W1  = (const float*)d_in[13];
  const float* bi1 = (const float*)d_in[14];
  const float* W2  = (const float*)d_in[15];
  const float* bi2 = (const float*)d_in[16];

  // ---- workspace layout (phase-aliased; total 17*32MB = 544 MB) ----
  char* ws = (char*)d_ws;
  const size_t MB32 = 33554432;     // 32 MiB
  u16* WqT = (u16*)(ws + 0*MB32);
  u16* WkT = (u16*)(ws + 1*MB32);
  u16* WvT = (u16*)(ws + 2*MB32);
  u16* WoT = (u16*)(ws + 3*MB32);
  u16* W1T = (u16*)(ws + 0*MB32);   // phase B: aliases WqT..WoT (dead)
  u16* xb  = (u16*)(ws + 4*MB32);
  u16* Qb  = (u16*)(ws + 5*MB32);
  u16* Kb  = (u16*)(ws + 6*MB32);
  u16* Vb  = (u16*)(ws + 7*MB32);
  u16* W2T = (u16*)(ws + 4*MB32);   // phase B: aliases xb..Vb (dead)
  u16* Vt  = (u16*)(ws + 8*MB32);
  float* scoresF = (float*)(ws + 9*MB32);
  u16* Pb  = (u16*)(ws + 10*MB32);
  u16* Ab  = (u16*)(ws + 10*MB32 + 16777216);
  u16* hB  = (u16*)(ws + 8*MB32);   // phase B: [8..12)*32MB region
  float* x1raw = (float*)(ws + 12*MB32);
  float* x2raw = (float*)(ws + 12*MB32); // aliases x1raw (dead after LN1)
  float* x1f   = (float*)(ws + 14*MB32);
  u16*   x1b   = (u16*)(ws + 16*MB32);

  const dim3 blk(256), blkG(512);
  const long long SD = (long long)S*D, SS = (long long)S*S, DS = (long long)D*S;

  // weights -> bf16 transposed [N][K]
  tr_f32_bf16<<<dim3(D/64, D/64), blk, 0, stream>>>(Wq, WqT, D, D);
  tr_f32_bf16<<<dim3(D/64, D/64), blk, 0, stream>>>(Wk, WkT, D, D);
  tr_f32_bf16<<<dim3(D/64, D/64), blk, 0, stream>>>(Wv, WvT, D, D);
  tr_f32_bf16<<<dim3(D/64, D/64), blk, 0, stream>>>(Wo, WoT, D, D);
  cvt_f32_bf16<<<dim3((NT*D/4)/256), blk, 0, stream>>>(x, xb, NT*D/4);

  // Q,K,V projections
  gemm256<1,0,0,0><<<dim3(D/256, NT/256, 1), blkG, 0, stream>>>(xb, WqT, bq,  nullptr, nullptr, Qb, NT, D, D, 1, 0,0,0);
  gemm256<1,0,0,0><<<dim3(D/256, NT/256, 1), blkG, 0, stream>>>(xb, WkT, bk,  nullptr, nullptr, Kb, NT, D, D, 1, 0,0,0);
  gemm256<1,0,0,0><<<dim3(D/256, NT/256, 1), blkG, 0, stream>>>(xb, WvT, bvp, nullptr, nullptr, Vb, NT, D, D, 1, 0,0,0);
  tr_bf16<<<dim3(D/64, S/64, B), blk, 0, stream>>>(Vb, Vt, S, D, SD, SD);

  // attention: scores = Q K^T (f32), softmax(1/64), P V
  gemm256<0,0,0,1><<<dim3(S/256, S/256, B), blkG, 0, stream>>>(Qb, Kb, nullptr, nullptr, scoresF, nullptr, S, S, D, 0, SD, SD, SS);
  softmax2048<<<dim3(B*S), blk, 0, stream>>>(scoresF, Pb, 0.015625f);
  gemm256<0,0,0,0><<<dim3(D/256, S/256, B), blkG, 0, stream>>>(Pb, Vt, nullptr, nullptr, nullptr, Ab, S, D, S, 0, SS, DS, SD);

  // O projection + residual, LN1
  gemm256<1,0,1,1><<<dim3(D/256, NT/256, 1), blkG, 0, stream>>>(Ab, WoT, bo, x, x1raw, nullptr, NT, D, D, 1, 0,0,0);
  layernorm4096<1><<<dim3(NT), blk, 0, stream>>>(x1raw, g1, b1, x1f, x1b);

  // FFN
  tr_f32_bf16<<<dim3(HD/64, D/64), blk, 0, stream>>>(W1, W1T, D, HD);
  gemm256<1,1,0,0><<<dim3(HD/256, NT/256, 1), blkG, 0, stream>>>(x1b, W1T, bi1, nullptr, nullptr, hB, NT, HD, D, 1, 0,0,0);
  tr_f32_bf16<<<dim3(D/64, HD/64), blk, 0, stream>>>(W2, W2T, HD, D);
  gemm256<1,0,1,1><<<dim3(D/256, NT/256, 1), blkG, 0, stream>>>(hB, W2T, bi2, x1f, x2raw, nullptr, NT, D, HD, 1, 0,0,0);
  layernorm4096<0><<<dim3(NT), blk, 0, stream>>>(x2raw, g2, b2, (float*)d_out, nullptr);
}